// Round 1
// baseline (379.316 us; speedup 1.0000x reference)
//
#include <hip/hip_runtime.h>
#include <math.h>

// Model: B=32, C=64, T=1024, H=10, OUT=2.
// Pipeline: embed+BN+tanh -> q,k,v (BN+relu/relu/tanh) -> LINEAR attention
// (collapsed to per-batch 10x10 M = K V^T, N = M Wc^T / H) -> BN+relu ->
// precomputed input currents -> sequential LSNN scan (ballot broadcast) with
// analytic LI readout weights g_t folded into spike accumulation.

constexpr int B = 32, C = 64, T = 1024, H = 10;
constexpr int BHT = B * H * T; // 327680

// workspace float offsets (overlapped lifetimes; total ~6.3 MB)
constexpr size_t OFF_PRE1 = 0;        // pre1 (K1..K3); reused for prec (K6..K8)
constexpr size_t OFF_PREQ = 327680;   // preq; reused for Iin (K8..K9), 524288 floats
constexpr size_t OFF_PREK = 655360;
constexpr size_t OFF_PREV = 983040;
constexpr size_t OFF_Q    = 1310720;  // q (K4..K6)
constexpr size_t OFF_ST1  = 1638400;  // mean[0..9], invstd[16..25] (32 floats each)
constexpr size_t OFF_STQ  = 1638432;
constexpr size_t OFF_STK  = 1638464;
constexpr size_t OFF_STV  = 1638496;
constexpr size_t OFF_STC  = 1638528;
constexpr size_t OFF_MP   = 1638560;  // M partials: 32 b * 4 chunks * 100
constexpr size_t OFF_G    = 1651360;  // g[1024]

// ---------------- K1: pre1[b,h,t] = sum_c beeg[b,c,t] W_ef[h,c] + b_ef[h]
__global__ __launch_bounds__(256) void k_embed(const float* __restrict__ beeg,
    const float* __restrict__ W_ef, const float* __restrict__ b_ef,
    float* __restrict__ pre1) {
  __shared__ float wl[H * C];
  for (int i = threadIdx.x; i < H * C; i += 256) wl[i] = W_ef[i];
  __syncthreads();
  int gid = blockIdx.x * 256 + threadIdx.x;  // b*T + t
  int b = gid >> 10, t = gid & 1023;
  float acc[H];
#pragma unroll
  for (int h = 0; h < H; ++h) acc[h] = b_ef[h];
  for (int c = 0; c < C; ++c) {
    float x = beeg[(size_t)(b * C + c) * T + t];
#pragma unroll
    for (int h = 0; h < H; ++h) acc[h] = fmaf(x, wl[h * C + c], acc[h]);
  }
#pragma unroll
  for (int h = 0; h < H; ++h) pre1[(size_t)(b * H + h) * T + t] = acc[h];
}

// ---------------- stats: one block per (tensor, channel); deterministic
__global__ __launch_bounds__(256) void k_stats(const float* __restrict__ X,
    float* __restrict__ st) {
  int tensor = blockIdx.x / 10, h = blockIdx.x % 10;
  const float* Xp = X + (size_t)tensor * BHT;
  double s = 0.0, sq = 0.0;
  for (int bb = 0; bb < B; ++bb) {
    const float* row = Xp + (size_t)(bb * H + h) * T;
    for (int t = threadIdx.x; t < T; t += 256) {
      double v = (double)row[t];
      s += v; sq += v * v;
    }
  }
  __shared__ double ls[256], lq[256];
  ls[threadIdx.x] = s; lq[threadIdx.x] = sq;
  __syncthreads();
  for (int off = 128; off; off >>= 1) {
    if (threadIdx.x < off) {
      ls[threadIdx.x] += ls[threadIdx.x + off];
      lq[threadIdx.x] += lq[threadIdx.x + off];
    }
    __syncthreads();
  }
  if (threadIdx.x == 0) {
    double mean = ls[0] / (double)(B * T);
    double var  = lq[0] / (double)(B * T) - mean * mean;
    float* o = st + (size_t)tensor * 32;
    o[h]      = (float)mean;
    o[16 + h] = (float)(1.0 / sqrt(var + 1e-5));
  }
}

// ---------------- K3: x = tanh(bn(pre1)); preq/prek/prev = Wq/Wk/Wv @ x
__global__ __launch_bounds__(256) void k_qkv_pre(const float* __restrict__ pre1,
    const float* __restrict__ st1, const float* __restrict__ g_i,
    const float* __restrict__ be_i, const float* __restrict__ Wq,
    const float* __restrict__ Wk, const float* __restrict__ Wv,
    float* __restrict__ preq, float* __restrict__ prek, float* __restrict__ prev) {
  int gid = blockIdx.x * 256 + threadIdx.x;
  int b = gid >> 10, t = gid & 1023;
  float x[H];
#pragma unroll
  for (int j = 0; j < H; ++j) {
    float p = pre1[(size_t)(b * H + j) * T + t];
    x[j] = tanhf(g_i[j] * (p - st1[j]) * st1[16 + j] + be_i[j]);
  }
  float aq[H], ak[H], av_[H];
#pragma unroll
  for (int h = 0; h < H; ++h) { aq[h] = 0.f; ak[h] = 0.f; av_[h] = 0.f; }
#pragma unroll
  for (int j = 0; j < H; ++j) {
#pragma unroll
    for (int h = 0; h < H; ++h) {
      aq[h]  = fmaf(x[j], Wq[h * H + j], aq[h]);
      ak[h]  = fmaf(x[j], Wk[h * H + j], ak[h]);
      av_[h] = fmaf(x[j], Wv[h * H + j], av_[h]);
    }
  }
#pragma unroll
  for (int h = 0; h < H; ++h) {
    size_t o = (size_t)(b * H + h) * T + t;
    preq[o] = aq[h]; prek[o] = ak[h]; prev[o] = av_[h];
  }
}

// ---------------- K5: activations; store q; M partials (deterministic)
__global__ __launch_bounds__(256) void k_act_M(const float* __restrict__ preq,
    const float* __restrict__ prek, const float* __restrict__ prev,
    const float* __restrict__ stq, const float* __restrict__ stk,
    const float* __restrict__ stv,
    const float* __restrict__ g_q, const float* __restrict__ be_q,
    const float* __restrict__ g_k, const float* __restrict__ be_k,
    const float* __restrict__ g_v, const float* __restrict__ be_v,
    float* __restrict__ qout, float* __restrict__ Mpart) {
  int bid = blockIdx.x;           // b*4 + chunk
  int b = bid >> 2, chunk = bid & 3;
  int t = chunk * 256 + threadIdx.x;
  float kx[H], vx[H];
#pragma unroll
  for (int h = 0; h < H; ++h) {
    size_t o = (size_t)(b * H + h) * T + t;
    float pq = preq[o], pk = prek[o], pv = prev[o];
    float qv = fmaxf(fmaf(g_q[h] * (pq - stq[h]), stq[16 + h], 0.f) + be_q[h], 0.f);
    // keep reference op order: g*(x-m)*invstd + be
    qv = fmaxf(g_q[h] * (pq - stq[h]) * stq[16 + h] + be_q[h], 0.f);
    qout[o] = qv;
    kx[h] = fmaxf(g_k[h] * (pk - stk[h]) * stk[16 + h] + be_k[h], 0.f);
    vx[h] = tanhf(g_v[h] * (pv - stv[h]) * stv[16 + h] + be_v[h]);
  }
  float m[H * H];
#pragma unroll
  for (int i = 0; i < H; ++i)
#pragma unroll
    for (int j = 0; j < H; ++j) m[i * H + j] = kx[i] * vx[j];
  // wave reduce (64 lanes)
#pragma unroll
  for (int e = 0; e < H * H; ++e)
    for (int off = 32; off; off >>= 1) m[e] += __shfl_down(m[e], off, 64);
  __shared__ float red[4][H * H];
  int wave = threadIdx.x >> 6, lane = threadIdx.x & 63;
  if (lane == 0) {
#pragma unroll
    for (int e = 0; e < H * H; ++e) red[wave][e] = m[e];
  }
  __syncthreads();
  if (threadIdx.x < H * H) {
    float sum = red[0][threadIdx.x] + red[1][threadIdx.x] +
                red[2][threadIdx.x] + red[3][threadIdx.x];
    Mpart[(size_t)bid * 100 + threadIdx.x] = sum;
  }
}

// ---------------- K6: N = (M @ Wc^T)/H per b (in LDS); prec = q . N
__global__ __launch_bounds__(256) void k_prec(const float* __restrict__ q,
    const float* __restrict__ Mpart, const float* __restrict__ Wc,
    float* __restrict__ prec) {
  int bid = blockIdx.x; int b = bid >> 2, chunk = bid & 3;
  __shared__ float Ms[H * H], Nl[H * H];
  if (threadIdx.x < H * H) {
    float s = 0.f;
#pragma unroll
    for (int c = 0; c < 4; ++c) s += Mpart[(size_t)(b * 4 + c) * 100 + threadIdx.x];
    Ms[threadIdx.x] = s;
  }
  __syncthreads();
  if (threadIdx.x < H * H) {
    int i = threadIdx.x / H, h = threadIdx.x % H;
    float a = 0.f;
#pragma unroll
    for (int j = 0; j < H; ++j) a = fmaf(Ms[i * H + j], Wc[h * H + j], a);
    Nl[threadIdx.x] = a * 0.1f;   // 1/H
  }
  __syncthreads();
  int t = chunk * 256 + threadIdx.x;
  float qv[H];
#pragma unroll
  for (int i = 0; i < H; ++i) qv[i] = q[(size_t)(b * H + i) * T + t];
#pragma unroll
  for (int h = 0; h < H; ++h) {
    float a = 0.f;
#pragma unroll
    for (int i = 0; i < H; ++i) a = fmaf(qv[i], Nl[i * H + h], a);
    prec[(size_t)(b * H + h) * T + t] = a;
  }
}

// ---------------- K8: xc = relu(bn(prec)); Iin[t][b][h] = W_in @ xc; g[t]
__global__ __launch_bounds__(256) void k_xc_iin(const float* __restrict__ prec,
    const float* __restrict__ stc, const float* __restrict__ g_c,
    const float* __restrict__ be_c, const float* __restrict__ W_in,
    float* __restrict__ Iin, float* __restrict__ g) {
  int gid = blockIdx.x * 256 + threadIdx.x;
  int b = gid >> 10, t = gid & 1023;
  float xc[H];
#pragma unroll
  for (int j = 0; j < H; ++j) {
    float p = prec[(size_t)(b * H + j) * T + t];
    xc[j] = fmaxf(g_c[j] * (p - stc[j]) * stc[16 + j] + be_c[j], 0.f);
  }
#pragma unroll
  for (int h = 0; h < H; ++h) {
    float a = 0.f;
#pragma unroll
    for (int j = 0; j < H; ++j) a = fmaf(xc[j], W_in[h * H + j], a);
    Iin[(size_t)(t * B + b) * 16 + h] = a;
  }
  if (gid < T) {
    // analytic LI readout weight: g[t] = (c/T) * G_{T-1-t}
    const double a_ = 0.9, d_ = 0.8, c_ = 0.1;
    int Mi = T - 1 - gid;
    double Ga = a_ * (1.0 - pow(a_, (double)(Mi + 1))) / (1.0 - a_);
    double Gd = d_ * (1.0 - pow(d_, (double)(Mi + 1))) / (1.0 - d_);
    g[gid] = (float)(c_ * (Ga - Gd) / (a_ - d_) / (double)T);
  }
}

// ---------------- K9: LSNN scan, one wave per batch element
__global__ __launch_bounds__(64) void k_scan(const float* __restrict__ Iin,
    const float* __restrict__ gw, const float* __restrict__ W_rec,
    const float* __restrict__ W_cls, const float* __restrict__ b_cls,
    float* __restrict__ out) {
  int b = blockIdx.x;
  int lane = threadIdx.x;
  bool act = lane < H;
  int hh = act ? lane : 0;
  float wr[H];
#pragma unroll
  for (int j = 0; j < H; ++j) wr[j] = act ? W_rec[hh * H + j] : 0.0f;
  float cur = 0.f, vm = 0.f, S = 0.f, gtot = 0.f;
  unsigned zm = 0u;  // spike bits 0..9, wave-uniform
  const float* ip = Iin + (size_t)b * 16 + hh;
  float ibuf[8], gbuf[8];
#pragma unroll
  for (int k = 0; k < 8; ++k) {
    ibuf[k] = ip[(size_t)k * (B * 16)];
    gbuf[k] = gw[k];
  }
  for (int t = 0; t < T; t += 8) {
#pragma unroll
    for (int u = 0; u < 8; ++u) {
      int tt = t + u;
      float iin = ibuf[u], gt = gbuf[u];
      int tn = (tt + 8) & (T - 1);               // branchless prefetch
      ibuf[u] = ip[(size_t)tn * (B * 16)];
      gbuf[u] = gw[tn];
      float rec = 0.f, rec2 = 0.f;
#pragma unroll
      for (int j = 0; j < H; j += 2) {
        rec  += ((zm >> j) & 1u)       ? wr[j]     : 0.f;
        rec2 += ((zm >> (j + 1)) & 1u) ? wr[j + 1] : 0.f;
      }
      float i_jump = cur + iin + (rec + rec2);
      float v_dec = fmaf(0.1f, i_jump - vm, vm);  // vm + 0.1*(i_jump - vm)
      cur = 0.8f * i_jump;                        // i_dec
      bool z = act && (v_dec > 0.5f);
      vm = z ? 0.f : v_dec;
      S += z ? gt : 0.f;
      gtot += gt;
      zm = (unsigned)__ballot(z);
    }
  }
  __shared__ float Sl[64];
  Sl[lane] = act ? S : 0.f;
  __syncthreads();
  if (lane < 2) {
    float a = 0.f;
#pragma unroll
    for (int h2 = 0; h2 < H; ++h2) a = fmaf(Sl[h2], W_cls[lane * H + h2], a);
    a += gtot * b_cls[lane];
    out[b * 2 + lane] = a;
  }
}

extern "C" void kernel_launch(void* const* d_in, const int* in_sizes, int n_in,
                              void* d_out, int out_size, void* d_ws, size_t ws_size,
                              hipStream_t stream) {
  const float* beeg  = (const float*)d_in[2];
  const float* W_ef  = (const float*)d_in[4];
  const float* b_ef  = (const float*)d_in[5];
  const float* g_i   = (const float*)d_in[6];
  const float* be_i  = (const float*)d_in[7];
  const float* Wq    = (const float*)d_in[8];
  const float* g_q   = (const float*)d_in[9];
  const float* be_q  = (const float*)d_in[10];
  const float* Wk    = (const float*)d_in[11];
  const float* g_k   = (const float*)d_in[12];
  const float* be_k  = (const float*)d_in[13];
  const float* Wv    = (const float*)d_in[14];
  const float* g_v   = (const float*)d_in[15];
  const float* be_v  = (const float*)d_in[16];
  const float* Wc    = (const float*)d_in[17];
  const float* g_c   = (const float*)d_in[18];
  const float* be_c  = (const float*)d_in[19];
  const float* W_in  = (const float*)d_in[20];
  const float* W_rec = (const float*)d_in[21];
  const float* W_cls = (const float*)d_in[22];
  const float* b_cls = (const float*)d_in[23];

  float* ws   = (float*)d_ws;
  float* pre1 = ws + OFF_PRE1;
  float* preq = ws + OFF_PREQ;
  float* prek = ws + OFF_PREK;
  float* prev = ws + OFF_PREV;
  float* q    = ws + OFF_Q;
  float* prec = ws + OFF_PRE1;   // reuse (pre1 dead after k_qkv_pre)
  float* Iin  = ws + OFF_PREQ;   // reuse (preq/prek dead after k_act_M)
  float* st1  = ws + OFF_ST1;
  float* stq  = ws + OFF_STQ;
  float* stk  = ws + OFF_STK;
  float* stv  = ws + OFF_STV;
  float* stc  = ws + OFF_STC;
  float* Mp   = ws + OFF_MP;
  float* g    = ws + OFF_G;

  k_embed<<<128, 256, 0, stream>>>(beeg, W_ef, b_ef, pre1);
  k_stats<<<10, 256, 0, stream>>>(pre1, st1);
  k_qkv_pre<<<128, 256, 0, stream>>>(pre1, st1, g_i, be_i, Wq, Wk, Wv,
                                     preq, prek, prev);
  k_stats<<<30, 256, 0, stream>>>(preq, stq);  // q,k,v contiguous (stride BHT)
  k_act_M<<<128, 256, 0, stream>>>(preq, prek, prev, stq, stk, stv,
                                   g_q, be_q, g_k, be_k, g_v, be_v, q, Mp);
  k_prec<<<128, 256, 0, stream>>>(q, Mp, Wc, prec);
  k_stats<<<10, 256, 0, stream>>>(prec, stc);
  k_xc_iin<<<128, 256, 0, stream>>>(prec, stc, g_c, be_c, W_in, Iin, g);
  k_scan<<<32, 64, 0, stream>>>(Iin, g, W_rec, W_cls, b_cls, (float*)d_out);
}